// Round 15
// baseline (300.717 us; speedup 1.0000x reference)
//
#include <hip/hip_runtime.h>

// B=32768, K=16, D=256, H=2, HD=128
#define Bsz 32768
#define SCALE 0.08838834764831845f   // 1/sqrt(128)

typedef __attribute__((ext_vector_type(4))) float f32x4;
typedef __attribute__((ext_vector_type(4))) unsigned short us4;
typedef __attribute__((ext_vector_type(4))) unsigned int ui4;
typedef __attribute__((ext_vector_type(2))) unsigned int ui2;
typedef _Float16 __attribute__((ext_vector_type(2))) h2;

static __device__ __forceinline__ unsigned int pk16(float a, float b){
  return __builtin_bit_cast(unsigned int, __builtin_amdgcn_cvt_pkrtz(a, b));
}
static __device__ __forceinline__ h2 uph(unsigned int u){
  return __builtin_bit_cast(h2, u);
}
static __device__ __forceinline__ float h2f(unsigned short h){
  return (float)__builtin_bit_cast(_Float16, h);
}
#define FDOT2(a, b, c) __builtin_amdgcn_fdot2((a), (b), (c), false)

// ---------------------------------------------------------------------------
// Prep (identical to passing rounds 12-14): f16 k-pair-packed weights, k-major.
//   W1P uint [128][640]: cols 0..511 -> M_h[k][m] (h=n>>8,m=n&255); 512..639 Wc
//   W2P uint [128][256]: Wv^T packed;  W3P uint [128][128]: Wx^T packed
// ---------------------------------------------------------------------------
__global__ void prep_kernel(const float* __restrict__ Wq, const float* __restrict__ Wk,
                            const float* __restrict__ Wv, const float* __restrict__ Wc,
                            const float* __restrict__ Wx, unsigned int* __restrict__ wsp){
  unsigned int* W1P = wsp;                 // [128][640]
  unsigned int* W2P = wsp + 128*640;       // [128][256]
  unsigned int* W3P = W2P + 128*256;       // [128][128]
  const int n = blockIdx.x;
  const int k = threadIdx.x;
  float val;
  if (n < 512){
    const int h = n >> 8, m = n & 255;
    const float* wq = Wq + h*128*256 + k;
    const float* wk = Wk + h*128*256 + m;
    float s = 0.f;
    for (int d = 0; d < 128; ++d) s += wq[d*256] * wk[d*256];
    val = s;
  } else if (n < 640){
    val = Wc[(n-512)*256 + k];
  } else if (n < 896){
    val = Wv[(n-640)*256 + k];
  } else {
    val = Wx[(n-896)*256 + k];
  }
  const float vo = __shfl_xor(val, 1, 64);
  if ((k & 1) == 0){
    const unsigned int p = pk16(val, vo);
    const int kp = k >> 1;
    if (n < 640)      W1P[kp*640 + n] = p;
    else if (n < 896) W2P[kp*256 + (n-640)] = p;
    else              W3P[kp*128 + (n-896)] = p;
  }
}

// ---------------------------------------------------------------------------
// A-kernel: ctil[32768][512] f16 (ws) + out-left. BR=32, 4 waves, zero
// barriers (wave owns rows 8w..8w+7). Same fdot2 math as round 12.
// LDS: s_c us[32][264] center f16 pairs only (16.9 KB).
// ctile uint layout: row*256 + tile*64 + ct*2 (tile = f16-col/128).
// ---------------------------------------------------------------------------
__global__ __launch_bounds__(256, 4) void a_kernel(
    const float* __restrict__ center, const unsigned int* __restrict__ Wall,
    unsigned int* __restrict__ ctileu, float* __restrict__ out)
{
  __shared__ __align__(16) unsigned short s_c[32*264];

  const int tid = threadIdx.x;
  const int b0  = blockIdx.x * 32;
  const unsigned int* W1P = Wall;          // [128][640]
  const int rt = tid >> 5;     // 0..7 (rows 4rt..4rt+3)
  const int ct = tid & 31;     // 0..31 (col quad)

  // stage center rows (wave-local) as packed f16 pairs
  {
    const int sr = tid >> 3;            // 0..31
    const int fc = (tid & 7) * 32;
    const float* cp = center + ((long)(b0 + sr) << 8) + fc;
    #pragma unroll
    for (int it = 0; it < 4; ++it){
      float4 a = *(const float4*)(cp + it*8);
      float4 b = *(const float4*)(cp + it*8 + 4);
      ui4 v = {pk16(a.x,a.y), pk16(a.z,a.w), pk16(b.x,b.y), pk16(b.z,b.w)};
      *(ui4*)&s_c[sr*264 + fc + it*8] = v;
    }
  }
  // no barrier: wave-local

  // pass 1: tiles {0,1,4} -> ctile cols 0..255 + out-left
  {
    f32x4 acc[4][3];
    #pragma unroll
    for (int rr = 0; rr < 4; ++rr)
      #pragma unroll
      for (int t = 0; t < 3; ++t) acc[rr][t] = (f32x4){0,0,0,0};
    #pragma unroll 1
    for (int k0 = 0; k0 < 256; k0 += 8){
      ui4 a8[4];
      #pragma unroll
      for (int rr = 0; rr < 4; ++rr)
        a8[rr] = *(const ui4*)&s_c[(4*rt+rr)*264 + k0];
      #pragma unroll
      for (int kp = 0; kp < 4; ++kp){
        const unsigned int* wrow = W1P + ((k0>>1) + kp)*640;
        const ui4 w0 = ((const ui4*)(wrow      ))[ct];
        const ui4 w1 = ((const ui4*)(wrow + 128))[ct];
        const ui4 w4 = ((const ui4*)(wrow + 512))[ct];
        #pragma unroll
        for (int rr = 0; rr < 4; ++rr){
          const h2 a2 = uph(a8[rr][kp]);
          #pragma unroll
          for (int j = 0; j < 4; ++j){
            acc[rr][0][j] = FDOT2(a2, uph(w0[j]), acc[rr][0][j]);
            acc[rr][1][j] = FDOT2(a2, uph(w1[j]), acc[rr][1][j]);
            acc[rr][2][j] = FDOT2(a2, uph(w4[j]), acc[rr][2][j]);
          }
        }
      }
    }
    #pragma unroll
    for (int rr = 0; rr < 4; ++rr){
      const long r = b0 + 4*rt + rr;
      ui2 v0 = {pk16(acc[rr][0][0], acc[rr][0][1]), pk16(acc[rr][0][2], acc[rr][0][3])};
      ui2 v1 = {pk16(acc[rr][1][0], acc[rr][1][1]), pk16(acc[rr][1][2], acc[rr][1][3])};
      *(ui2*)&ctileu[r*256 +      ct*2] = v0;       // tile 0
      *(ui2*)&ctileu[r*256 + 64 + ct*2] = v1;       // tile 1
      *(f32x4*)&out[(r << 8) + ct*4] = acc[rr][2];  // out-left
    }
  }

  // pass 2: tiles {2,3} -> ctile cols 256..511
  {
    f32x4 acc[4][2];
    #pragma unroll
    for (int rr = 0; rr < 4; ++rr){ acc[rr][0] = (f32x4){0,0,0,0}; acc[rr][1] = (f32x4){0,0,0,0}; }
    #pragma unroll 1
    for (int k0 = 0; k0 < 256; k0 += 8){
      ui4 a8[4];
      #pragma unroll
      for (int rr = 0; rr < 4; ++rr)
        a8[rr] = *(const ui4*)&s_c[(4*rt+rr)*264 + k0];
      #pragma unroll
      for (int kp = 0; kp < 4; ++kp){
        const unsigned int* wrow = W1P + ((k0>>1) + kp)*640;
        const ui4 w2 = ((const ui4*)(wrow + 256))[ct];
        const ui4 w3 = ((const ui4*)(wrow + 384))[ct];
        #pragma unroll
        for (int rr = 0; rr < 4; ++rr){
          const h2 a2 = uph(a8[rr][kp]);
          #pragma unroll
          for (int j = 0; j < 4; ++j){
            acc[rr][0][j] = FDOT2(a2, uph(w2[j]), acc[rr][0][j]);
            acc[rr][1][j] = FDOT2(a2, uph(w3[j]), acc[rr][1][j]);
          }
        }
      }
    }
    #pragma unroll
    for (int rr = 0; rr < 4; ++rr){
      const long r = b0 + 4*rt + rr;
      ui2 v0 = {pk16(acc[rr][0][0], acc[rr][0][1]), pk16(acc[rr][0][2], acc[rr][0][3])};
      ui2 v1 = {pk16(acc[rr][1][0], acc[rr][1][1]), pk16(acc[rr][1][2], acc[rr][1][3])};
      *(ui2*)&ctileu[r*256 + 128 + ct*2] = v0;      // tile 2
      *(ui2*)&ctileu[r*256 + 192 + ct*2] = v1;      // tile 3
    }
  }
}

// ---------------------------------------------------------------------------
// B-kernel: attention + ctx@Wv + fused LN + out-right. BR=16 rows/block,
// 128 threads (2 waves), wave owns rows 8w..8w+7, zero barriers.
// ctil read from global (L2/L3-resident, written by a_kernel).
// LDS s2 us[16][520]/row: agg0 [0..255], wbuf+agg1 [256..511] (B..C),
// ctx_n [0..255] (C..E overlay after full agg read).
// ---------------------------------------------------------------------------
__global__ __launch_bounds__(128, 4) void b_kernel(
    const float* __restrict__ nbr, const float* __restrict__ ew,
    const float* __restrict__ gamma, const float* __restrict__ beta,
    const unsigned int* __restrict__ Wall, const unsigned int* __restrict__ ctileu,
    float* __restrict__ out)
{
  __shared__ __align__(16) unsigned short s2[16*520];

  const int tid  = threadIdx.x;
  const int wid  = tid >> 6;    // 0..1
  const int lane = tid & 63;
  const int b0   = blockIdx.x * 16;

  const unsigned int* W2P = Wall + 128*640;     // [128][256]
  const unsigned int* W3P = W2P + 128*256;      // [128][128]

  const int rt = tid >> 5;     // 0..3 (rows 4rt..4rt+3)
  const int ct = lane & 31;    // 0..31 (col quad)

  // ---- Phase B: attention, 8 rows/wave ----
  {
    const int myk = ((lane>>4)&1)*8 + ((lane>>3)&1)*4 + ((lane>>2)&1)*2 + ((lane>>1)&1);
    const int myh = lane >> 5;
    #pragma unroll 1
    for (int rr = 0; rr < 8; ++rr){
      const int r = wid*8 + rr;
      const long b = b0 + r;
      float4 c0, c1;
      {
        ui2 u0 = *(const ui2*)&ctileu[b*256 + lane*2];        // cols lane*4..+3
        ui2 u1 = *(const ui2*)&ctileu[b*256 + 128 + lane*2];  // cols 256+lane*4..
        h2 p0 = uph(u0[0]), p1 = uph(u0[1]), p2 = uph(u1[0]), p3 = uph(u1[1]);
        c0.x=(float)p0[0]; c0.y=(float)p0[1]; c0.z=(float)p1[0]; c0.w=(float)p1[1];
        c1.x=(float)p2[0]; c1.y=(float)p2[1]; c1.z=(float)p3[0]; c1.w=(float)p3[1];
      }
      float4 xv[16];
      const float* npt = nbr + ((b << 4) << 8) + lane*4;
      #pragma unroll
      for (int k = 0; k < 16; ++k) xv[k] = *(const float4*)(npt + (k << 8));
      float P0[16], P1[16];
      #pragma unroll
      for (int k = 0; k < 16; ++k){
        P0[k] = xv[k].x*c0.x + xv[k].y*c0.y + xv[k].z*c0.z + xv[k].w*c0.w;
        P1[k] = xv[k].x*c1.x + xv[k].y*c1.y + xv[k].z*c1.z + xv[k].w*c1.w;
      }
      // reduce-scatter: masks 32,16,8,4,2, then final 1
      const int b5 = lane & 32, b4 = lane & 16, b3 = lane & 8, b2 = lane & 4, b1 = lane & 2;
      float Q[16];
      #pragma unroll
      for (int j = 0; j < 16; ++j){
        const float give = b5 ? P0[j] : P1[j];
        const float keep = b5 ? P1[j] : P0[j];
        Q[j] = keep + __shfl_xor(give, 32, 64);
      }
      float R[8];
      #pragma unroll
      for (int j = 0; j < 8; ++j){
        const float give = b4 ? Q[j] : Q[8+j];
        const float keep = b4 ? Q[8+j] : Q[j];
        R[j] = keep + __shfl_xor(give, 16, 64);
      }
      float S[4];
      #pragma unroll
      for (int j = 0; j < 4; ++j){
        const float give = b3 ? R[j] : R[4+j];
        const float keep = b3 ? R[4+j] : R[j];
        S[j] = keep + __shfl_xor(give, 8, 64);
      }
      float T[2];
      #pragma unroll
      for (int j = 0; j < 2; ++j){
        const float give = b2 ? S[j] : S[2+j];
        const float keep = b2 ? S[2+j] : S[j];
        T[j] = keep + __shfl_xor(give, 4, 64);
      }
      float U;
      {
        const float give = b1 ? T[0] : T[1];
        const float keep = b1 ? T[1] : T[0];
        U = keep + __shfl_xor(give, 2, 64);
      }
      const float sfull = U + __shfl_xor(U, 1, 64);   // s[myh][myk]
      const float erk = ew[b*16 + myk];
      const float e = __expf(sfull*SCALE + erk);      // scores O(1): no max-sub
      float dn = e;
      dn += __shfl_xor(dn, 2, 64);
      dn += __shfl_xor(dn, 4, 64);
      dn += __shfl_xor(dn, 8, 64);
      dn += __shfl_xor(dn, 16, 64);
      const float w = e / dn;
      float* wbuf = (float*)&s2[r*520 + 256];
      wbuf[myh*16 + myk] = w;                         // 2 lanes same addr, same value
      f32x4 wv[8];
      #pragma unroll
      for (int t = 0; t < 8; ++t) wv[t] = ((const f32x4*)wbuf)[t];
      float4 agg0 = {0,0,0,0}, agg1 = {0,0,0,0};
      #pragma unroll
      for (int k = 0; k < 16; ++k){
        const float w0 = wv[k>>2][k&3];
        const float w1 = wv[4 + (k>>2)][k&3];
        agg0.x += w0*xv[k].x; agg0.y += w0*xv[k].y; agg0.z += w0*xv[k].z; agg0.w += w0*xv[k].w;
        agg1.x += w1*xv[k].x; agg1.y += w1*xv[k].y; agg1.z += w1*xv[k].z; agg1.w += w1*xv[k].w;
      }
      ui2 v0 = {pk16(agg0.x, agg0.y), pk16(agg0.z, agg0.w)};
      ui2 v1 = {pk16(agg1.x, agg1.y), pk16(agg1.z, agg1.w)};
      *(ui2*)&s2[r*520 + lane*4]       = v0;   // agg0
      *(ui2*)&s2[r*520 + 256 + lane*4] = v1;   // agg1 (overwrites wbuf after read)
    }
  }
  // no barrier: agg rows wave-local

  // ---- Phase C (+fused LayerNorm): ctx in regs -> ctx_n packed f16 ----
  {
    f32x4 cacc[4][2];
    #pragma unroll
    for (int rr = 0; rr < 4; ++rr){ cacc[rr][0] = (f32x4){0,0,0,0}; cacc[rr][1] = (f32x4){0,0,0,0}; }
    #pragma unroll 1
    for (int k0 = 0; k0 < 256; k0 += 8){
      ui4 a0[4], a1[4];
      #pragma unroll
      for (int rr = 0; rr < 4; ++rr){
        a0[rr] = *(const ui4*)&s2[(4*rt+rr)*520 + k0];
        a1[rr] = *(const ui4*)&s2[(4*rt+rr)*520 + 256 + k0];
      }
      #pragma unroll
      for (int kp = 0; kp < 4; ++kp){
        const unsigned int* wrow = W2P + ((k0>>1) + kp)*256;
        const ui4 w0 = ((const ui4*)(wrow      ))[ct];   // ctx cols 0..127 (head0)
        const ui4 w1 = ((const ui4*)(wrow + 128))[ct];   // ctx cols 128..255 (head1)
        #pragma unroll
        for (int rr = 0; rr < 4; ++rr){
          const h2 x0 = uph(a0[rr][kp]);
          const h2 x1 = uph(a1[rr][kp]);
          #pragma unroll
          for (int j = 0; j < 4; ++j){
            cacc[rr][0][j] = FDOT2(x0, uph(w0[j]), cacc[rr][0][j]);
            cacc[rr][1][j] = FDOT2(x1, uph(w1[j]), cacc[rr][1][j]);
          }
        }
      }
    }
    const f32x4 gv0 = ((const f32x4*)gamma)[ct], gv1 = ((const f32x4*)gamma)[32 + ct];
    const f32x4 bv0 = ((const f32x4*)beta )[ct], bv1 = ((const f32x4*)beta )[32 + ct];
    #pragma unroll
    for (int rr = 0; rr < 4; ++rr){
      float s = 0.f, q = 0.f;
      #pragma unroll
      for (int t = 0; t < 2; ++t)
        #pragma unroll
        for (int j = 0; j < 4; ++j){
          const float x = cacc[rr][t][j];
          s += x; q += x*x;
        }
      #pragma unroll
      for (int m = 16; m >= 1; m >>= 1){
        s += __shfl_xor(s, m, 64);
        q += __shfl_xor(q, m, 64);
      }
      const float mu  = s * (1.f/256.f);
      const float var = q * (1.f/256.f) - mu*mu;
      const float rs  = rsqrtf(var + 1e-5f);
      const int r = 4*rt + rr;
      float y0[4], y1[4];
      #pragma unroll
      for (int j = 0; j < 4; ++j){
        y0[j] = (cacc[rr][0][j] - mu)*rs*gv0[j] + bv0[j];
        y1[j] = (cacc[rr][1][j] - mu)*rs*gv1[j] + bv1[j];
      }
      ui2 v0 = {pk16(y0[0], y0[1]), pk16(y0[2], y0[3])};
      ui2 v1 = {pk16(y1[0], y1[1]), pk16(y1[2], y1[3])};
      *(ui2*)&s2[r*520 + ct*4]       = v0;   // ctx_n cols ct*4..+3
      *(ui2*)&s2[r*520 + 128 + ct*4] = v1;   // ctx_n cols 128+..
    }
  }
  // no barrier: ctx_n rows wave-local

  // ---- Phase E: out-right = ctx_n @ Wx^T ----
  {
    f32x4 eacc[4];
    #pragma unroll
    for (int rr = 0; rr < 4; ++rr) eacc[rr] = (f32x4){0,0,0,0};
    #pragma unroll 1
    for (int k0 = 0; k0 < 256; k0 += 8){
      ui4 a8[4];
      #pragma unroll
      for (int rr = 0; rr < 4; ++rr)
        a8[rr] = *(const ui4*)&s2[(4*rt+rr)*520 + k0];
      #pragma unroll
      for (int kp = 0; kp < 4; ++kp){
        const ui4 w = ((const ui4*)(W3P + ((k0>>1) + kp)*128))[ct];
        #pragma unroll
        for (int rr = 0; rr < 4; ++rr){
          const h2 x = uph(a8[rr][kp]);
          #pragma unroll
          for (int j = 0; j < 4; ++j)
            eacc[rr][j] = FDOT2(x, uph(w[j]), eacc[rr][j]);
        }
      }
    }
    #pragma unroll
    for (int rr = 0; rr < 4; ++rr)
      *(f32x4*)&out[((long)(b0 + 4*rt + rr) << 8) + 128 + ct*4] = eacc[rr];
  }
}

extern "C" void kernel_launch(void* const* d_in, const int* in_sizes, int n_in,
                              void* d_out, int out_size, void* d_ws, size_t ws_size,
                              hipStream_t stream){
  const float* center = (const float*)d_in[0];
  const float* nbr    = (const float*)d_in[1];
  const float* ew     = (const float*)d_in[2];
  const float* Wq     = (const float*)d_in[3];
  const float* Wk     = (const float*)d_in[4];
  const float* Wv     = (const float*)d_in[5];
  const float* Wc     = (const float*)d_in[6];
  const float* Wx     = (const float*)d_in[7];
  const float* gamma  = (const float*)d_in[8];
  const float* beta   = (const float*)d_in[9];
  (void)in_sizes; (void)n_in; (void)out_size;

  unsigned int* W  = (unsigned int*)d_ws;            // 512 KiB weights
  unsigned int* CT = W + 131072;                     // ctil f16: 32768*256 uints = 33.5 MB
  (void)ws_size;                                     // observed ws ≈ 2 GB

  prep_kernel<<<1024, 256, 0, stream>>>(Wq, Wk, Wv, Wc, Wx, W);
  a_kernel<<<Bsz/32, 256, 0, stream>>>(center, W, CT, (float*)d_out);
  b_kernel<<<Bsz/16, 128, 0, stream>>>(nbr, ew, gamma, beta, W, CT, (float*)d_out);
}

// Round 16
// 294.724 us; speedup vs baseline: 1.0203x; 1.0203x over previous
//
#include <hip/hip_runtime.h>

// B=32768, K=16, D=256, H=2, HD=128
#define Bsz 32768
#define BR  32           // rows per block; 8 rows per wave, wave-autonomous
#define SCALE 0.08838834764831845f   // 1/sqrt(128)

typedef __attribute__((ext_vector_type(4))) float f32x4;
typedef __attribute__((ext_vector_type(4))) unsigned short us4;
typedef __attribute__((ext_vector_type(4))) unsigned int ui4;
typedef __attribute__((ext_vector_type(2))) unsigned int ui2;
typedef _Float16 __attribute__((ext_vector_type(2))) h2;

static __device__ __forceinline__ unsigned int pk16(float a, float b){
  return __builtin_bit_cast(unsigned int, __builtin_amdgcn_cvt_pkrtz(a, b));
}
static __device__ __forceinline__ h2 uph(unsigned int u){
  return __builtin_bit_cast(h2, u);
}
#define FDOT2(a, b, c) __builtin_amdgcn_fdot2((a), (b), (c), false)

// ---------------------------------------------------------------------------
// Prep (identical to passing rounds 12-15): f16 k-pair-packed weights, k-major.
//   W1P uint [128][640]: cols 0..511 -> M_h[k][m] (h=n>>8,m=n&255); 512..639 Wc
//   W2P uint [128][256]: Wv^T packed;  W3P uint [128][128]: Wx^T packed
// ---------------------------------------------------------------------------
__global__ void prep_kernel(const float* __restrict__ Wq, const float* __restrict__ Wk,
                            const float* __restrict__ Wv, const float* __restrict__ Wc,
                            const float* __restrict__ Wx, unsigned int* __restrict__ wsp){
  unsigned int* W1P = wsp;                 // [128][640]
  unsigned int* W2P = wsp + 128*640;       // [128][256]
  unsigned int* W3P = W2P + 128*256;       // [128][128]
  const int n = blockIdx.x;
  const int k = threadIdx.x;
  float val;
  if (n < 512){
    const int h = n >> 8, m = n & 255;
    const float* wq = Wq + h*128*256 + k;
    const float* wk = Wk + h*128*256 + m;
    float s = 0.f;
    for (int d = 0; d < 128; ++d) s += wq[d*256] * wk[d*256];
    val = s;
  } else if (n < 640){
    val = Wc[(n-512)*256 + k];
  } else if (n < 896){
    val = Wv[(n-640)*256 + k];
  } else {
    val = Wx[(n-896)*256 + k];
  }
  const float vo = __shfl_xor(val, 1, 64);
  if ((k & 1) == 0){
    const unsigned int p = pk16(val, vo);
    const int kp = k >> 1;
    if (n < 640)      W1P[kp*640 + n] = p;
    else if (n < 896) W2P[kp*256 + (n-640)] = p;
    else              W3P[kp*128 + (n-896)] = p;
  }
}

// ---------------------------------------------------------------------------
// Fused kernel = round 12 (BR=32, 4 waves, ZERO BARRIERS, wave w owns rows
// 8w..8w+7, fdot2 GEMMs, single 33.3 KB LDS, 4 blocks/CU) with phase B
// SOFTWARE-PIPELINED: rotating f32 xv buffer (row rr+1's HBM loads issue
// mid-row-rr and are covered by the reduction chain + aggregate).
// ---------------------------------------------------------------------------
__global__ __launch_bounds__(256, 4) void fused_kernel(
    const float* __restrict__ center, const float* __restrict__ nbr,
    const float* __restrict__ ew, const float* __restrict__ gamma,
    const float* __restrict__ beta, const unsigned int* __restrict__ Wall,
    float* __restrict__ out)
{
  __shared__ __align__(16) unsigned short s_ctil[BR*520];

  const int tid  = threadIdx.x;
  const int wid  = tid >> 6;
  const int lane = tid & 63;
  const int b0   = blockIdx.x * BR;

  const unsigned int* W1P = Wall;               // [128][640]
  const unsigned int* W2P = Wall + 128*640;     // [128][256]
  const unsigned int* W3P = W2P + 128*256;      // [128][128]

  const int rt = tid >> 5;     // 0..7  (rows 4rt..4rt+3)
  const int ct = tid & 31;     // 0..31 (col quad)

  // ---- stage center rows 8w..8w+7 as packed f16 pairs -> cells 256..511 ----
  {
    const int sr = tid >> 3;            // 0..31, wave-local rows
    const int fc = (tid & 7) * 32;      // float col base
    const float* cp = center + ((long)(b0 + sr) << 8) + fc;
    #pragma unroll
    for (int it = 0; it < 4; ++it){
      float4 a = *(const float4*)(cp + it*8);
      float4 b = *(const float4*)(cp + it*8 + 4);
      ui4 v = {pk16(a.x,a.y), pk16(a.z,a.w), pk16(b.x,b.y), pk16(b.z,b.w)};
      *(ui4*)&s_ctil[sr*520 + 256 + fc + it*8] = v;
    }
  }
  // no barrier: wave-local

  // ---- Phase A pass 1: tiles {0,1,4} -> ctil cols 0..255 + out-left ----
  {
    f32x4 acc[4][3];
    #pragma unroll
    for (int rr = 0; rr < 4; ++rr)
      #pragma unroll
      for (int t = 0; t < 3; ++t) acc[rr][t] = (f32x4){0,0,0,0};
    #pragma unroll 1
    for (int k0 = 0; k0 < 256; k0 += 8){
      ui4 a8[4];
      #pragma unroll
      for (int rr = 0; rr < 4; ++rr)
        a8[rr] = *(const ui4*)&s_ctil[(4*rt+rr)*520 + 256 + k0];
      #pragma unroll
      for (int kp = 0; kp < 4; ++kp){
        const unsigned int* wrow = W1P + ((k0>>1) + kp)*640;
        const ui4 w0 = ((const ui4*)(wrow      ))[ct];
        const ui4 w1 = ((const ui4*)(wrow + 128))[ct];
        const ui4 w4 = ((const ui4*)(wrow + 512))[ct];
        #pragma unroll
        for (int rr = 0; rr < 4; ++rr){
          const h2 a2 = uph(a8[rr][kp]);
          #pragma unroll
          for (int j = 0; j < 4; ++j){
            acc[rr][0][j] = FDOT2(a2, uph(w0[j]), acc[rr][0][j]);
            acc[rr][1][j] = FDOT2(a2, uph(w1[j]), acc[rr][1][j]);
            acc[rr][2][j] = FDOT2(a2, uph(w4[j]), acc[rr][2][j]);
          }
        }
      }
    }
    #pragma unroll
    for (int rr = 0; rr < 4; ++rr){
      const int r = 4*rt + rr;
      ui2 v0 = {pk16(acc[rr][0][0], acc[rr][0][1]), pk16(acc[rr][0][2], acc[rr][0][3])};
      ui2 v1 = {pk16(acc[rr][1][0], acc[rr][1][1]), pk16(acc[rr][1][2], acc[rr][1][3])};
      *(ui2*)&s_ctil[r*520 + ct*4]       = v0;    // ctil cols ct*4..+3
      *(ui2*)&s_ctil[r*520 + 128 + ct*4] = v1;    // ctil cols 128+..
      *(f32x4*)&out[((long)(b0 + r) << 8) + ct*4] = acc[rr][2];
    }
  }

  // ---- Phase A pass 2: tiles {2,3} -> ctil cols 256..511 (post-loop write) ----
  {
    f32x4 acc[4][2];
    #pragma unroll
    for (int rr = 0; rr < 4; ++rr){ acc[rr][0] = (f32x4){0,0,0,0}; acc[rr][1] = (f32x4){0,0,0,0}; }
    #pragma unroll 1
    for (int k0 = 0; k0 < 256; k0 += 8){
      ui4 a8[4];
      #pragma unroll
      for (int rr = 0; rr < 4; ++rr)
        a8[rr] = *(const ui4*)&s_ctil[(4*rt+rr)*520 + 256 + k0];
      #pragma unroll
      for (int kp = 0; kp < 4; ++kp){
        const unsigned int* wrow = W1P + ((k0>>1) + kp)*640;
        const ui4 w2 = ((const ui4*)(wrow + 256))[ct];
        const ui4 w3 = ((const ui4*)(wrow + 384))[ct];
        #pragma unroll
        for (int rr = 0; rr < 4; ++rr){
          const h2 a2 = uph(a8[rr][kp]);
          #pragma unroll
          for (int j = 0; j < 4; ++j){
            acc[rr][0][j] = FDOT2(a2, uph(w2[j]), acc[rr][0][j]);
            acc[rr][1][j] = FDOT2(a2, uph(w3[j]), acc[rr][1][j]);
          }
        }
      }
    }
    // all center reads done; safe to overwrite cells 256..511 (same wave)
    #pragma unroll
    for (int rr = 0; rr < 4; ++rr){
      const int r = 4*rt + rr;
      ui2 v0 = {pk16(acc[rr][0][0], acc[rr][0][1]), pk16(acc[rr][0][2], acc[rr][0][3])};
      ui2 v1 = {pk16(acc[rr][1][0], acc[rr][1][1]), pk16(acc[rr][1][2], acc[rr][1][3])};
      *(ui2*)&s_ctil[r*520 + 256 + ct*4] = v0;    // ctil cols 256+..
      *(ui2*)&s_ctil[r*520 + 384 + ct*4] = v1;    // ctil cols 384+..
    }
  }
  // no barrier: ctil rows wave-local

  // ---- Phase B: attention, 8 rows/wave, SOFTWARE-PIPELINED xv ----
  {
    const int myk = ((lane>>4)&1)*8 + ((lane>>3)&1)*4 + ((lane>>2)&1)*2 + ((lane>>1)&1);
    const int myh = lane >> 5;
    float4 xv[16];                       // rotating f32 buffer (row rr's data)
    {
      const float* npt0 = nbr + (((long)(b0 + wid*8)) << 12) + lane*4;
      #pragma unroll
      for (int k = 0; k < 16; ++k) xv[k] = *(const float4*)(npt0 + (k << 8));
    }
    #pragma unroll 1
    for (int rr = 0; rr < 8; ++rr){
      const int r = wid*8 + rr;
      const long b = b0 + r;
      // c (f16 pairs straight from LDS)
      ui2 u0 = *(const ui2*)&s_ctil[r*520 + lane*4];
      ui2 u1 = *(const ui2*)&s_ctil[r*520 + 256 + lane*4];
      const h2 c00 = uph(u0[0]), c01 = uph(u0[1]);
      const h2 c10 = uph(u1[0]), c11 = uph(u1[1]);
      // pack xv -> f16 pairs (f32 buffer dead after this)
      ui2 xvp[16];
      #pragma unroll
      for (int k = 0; k < 16; ++k)
        xvp[k] = (ui2){pk16(xv[k].x, xv[k].y), pk16(xv[k].z, xv[k].w)};
      // P via fdot2 on packed pairs
      float P0[16], P1[16];
      #pragma unroll
      for (int k = 0; k < 16; ++k){
        const h2 xa = uph(xvp[k][0]), xb = uph(xvp[k][1]);
        P0[k] = FDOT2(xb, c01, FDOT2(xa, c00, 0.f));
        P1[k] = FDOT2(xb, c11, FDOT2(xa, c10, 0.f));
      }
      // reduce-scatter step 1+2 (P -> Q -> R)
      const int b5 = lane & 32, b4 = lane & 16, b3 = lane & 8, b2 = lane & 4, b1 = lane & 2;
      float Q[16];
      #pragma unroll
      for (int j = 0; j < 16; ++j){
        const float give = b5 ? P0[j] : P1[j];
        const float keep = b5 ? P1[j] : P0[j];
        Q[j] = keep + __shfl_xor(give, 32, 64);
      }
      float R[8];
      #pragma unroll
      for (int j = 0; j < 8; ++j){
        const float give = b4 ? Q[j] : Q[8+j];
        const float keep = b4 ? Q[8+j] : Q[j];
        R[j] = keep + __shfl_xor(give, 16, 64);
      }
      // issue NEXT row's loads into the (dead) f32 buffer; latency covered
      // by the remaining chain + aggregate (~600-800 cyc)
      if (rr < 7){
        const float* nptn = nbr + ((b + 1) << 12) + lane*4;
        #pragma unroll
        for (int k = 0; k < 16; ++k) xv[k] = *(const float4*)(nptn + (k << 8));
      }
      float S[4];
      #pragma unroll
      for (int j = 0; j < 4; ++j){
        const float give = b3 ? R[j] : R[4+j];
        const float keep = b3 ? R[4+j] : R[j];
        S[j] = keep + __shfl_xor(give, 8, 64);
      }
      float T[2];
      #pragma unroll
      for (int j = 0; j < 2; ++j){
        const float give = b2 ? S[j] : S[2+j];
        const float keep = b2 ? S[2+j] : S[j];
        T[j] = keep + __shfl_xor(give, 4, 64);
      }
      float U;
      {
        const float give = b1 ? T[0] : T[1];
        const float keep = b1 ? T[1] : T[0];
        U = keep + __shfl_xor(give, 2, 64);
      }
      const float sfull = U + __shfl_xor(U, 1, 64);   // s[myh][myk]
      const float erk = ew[b*16 + myk];
      const float e = __expf(sfull*SCALE + erk);      // scores O(1): no max-sub
      float dn = e;
      dn += __shfl_xor(dn, 2, 64);
      dn += __shfl_xor(dn, 4, 64);
      dn += __shfl_xor(dn, 8, 64);
      dn += __shfl_xor(dn, 16, 64);
      const float w = e / dn;
      // broadcast via wave-local overlay of head1-ctil cells (c1 already read)
      float* wbuf = (float*)&s_ctil[r*520 + 256];
      wbuf[myh*16 + myk] = w;                         // 2 lanes same addr, same value
      f32x4 wv[8];
      #pragma unroll
      for (int t = 0; t < 8; ++t) wv[t] = ((const f32x4*)wbuf)[t];
      // aggregate from packed f16 xv
      float4 agg0 = {0,0,0,0}, agg1 = {0,0,0,0};
      #pragma unroll
      for (int k = 0; k < 16; ++k){
        const float w0 = wv[k>>2][k&3];
        const float w1 = wv[4 + (k>>2)][k&3];
        const h2 pa = uph(xvp[k][0]), pb = uph(xvp[k][1]);
        const float x0 = (float)pa[0], x1 = (float)pa[1];
        const float x2 = (float)pb[0], x3 = (float)pb[1];
        agg0.x += w0*x0; agg0.y += w0*x1; agg0.z += w0*x2; agg0.w += w0*x3;
        agg1.x += w1*x0; agg1.y += w1*x1; agg1.z += w1*x2; agg1.w += w1*x3;
      }
      ui2 v0 = {pk16(agg0.x, agg0.y), pk16(agg0.z, agg0.w)};
      ui2 v1 = {pk16(agg1.x, agg1.y), pk16(agg1.z, agg1.w)};
      *(ui2*)&s_ctil[r*520 + lane*4]       = v0;   // agg0 (WAR on own cells)
      *(ui2*)&s_ctil[r*520 + 256 + lane*4] = v1;   // agg1 (overwrites wbuf after read)
    }
  }
  // no barrier: agg rows wave-local

  // ---- Phase C (+fused LayerNorm): ctx in registers -> ctx_n packed f16 ----
  {
    f32x4 cacc[4][2];
    #pragma unroll
    for (int rr = 0; rr < 4; ++rr){ cacc[rr][0] = (f32x4){0,0,0,0}; cacc[rr][1] = (f32x4){0,0,0,0}; }
    #pragma unroll 1
    for (int k0 = 0; k0 < 256; k0 += 8){
      ui4 a0[4], a1[4];
      #pragma unroll
      for (int rr = 0; rr < 4; ++rr){
        a0[rr] = *(const ui4*)&s_ctil[(4*rt+rr)*520 + k0];
        a1[rr] = *(const ui4*)&s_ctil[(4*rt+rr)*520 + 256 + k0];
      }
      #pragma unroll
      for (int kp = 0; kp < 4; ++kp){
        const unsigned int* wrow = W2P + ((k0>>1) + kp)*256;
        const ui4 w0 = ((const ui4*)(wrow      ))[ct];   // ctx cols 0..127 (head0)
        const ui4 w1 = ((const ui4*)(wrow + 128))[ct];   // ctx cols 128..255 (head1)
        #pragma unroll
        for (int rr = 0; rr < 4; ++rr){
          const h2 x0 = uph(a0[rr][kp]);
          const h2 x1 = uph(a1[rr][kp]);
          #pragma unroll
          for (int j = 0; j < 4; ++j){
            cacc[rr][0][j] = FDOT2(x0, uph(w0[j]), cacc[rr][0][j]);
            cacc[rr][1][j] = FDOT2(x1, uph(w1[j]), cacc[rr][1][j]);
          }
        }
      }
    }
    // fused LayerNorm across the 32 ct-lanes of each rt group
    const f32x4 gv0 = ((const f32x4*)gamma)[ct], gv1 = ((const f32x4*)gamma)[32 + ct];
    const f32x4 bv0 = ((const f32x4*)beta )[ct], bv1 = ((const f32x4*)beta )[32 + ct];
    #pragma unroll
    for (int rr = 0; rr < 4; ++rr){
      float s = 0.f, q = 0.f;
      #pragma unroll
      for (int t = 0; t < 2; ++t)
        #pragma unroll
        for (int j = 0; j < 4; ++j){
          const float x = cacc[rr][t][j];
          s += x; q += x*x;
        }
      #pragma unroll
      for (int m = 16; m >= 1; m >>= 1){
        s += __shfl_xor(s, m, 64);
        q += __shfl_xor(q, m, 64);
      }
      const float mu  = s * (1.f/256.f);
      const float var = q * (1.f/256.f) - mu*mu;
      const float rs  = rsqrtf(var + 1e-5f);
      const int r = 4*rt + rr;
      float y0[4], y1[4];
      #pragma unroll
      for (int j = 0; j < 4; ++j){
        y0[j] = (cacc[rr][0][j] - mu)*rs*gv0[j] + bv0[j];
        y1[j] = (cacc[rr][1][j] - mu)*rs*gv1[j] + bv1[j];
      }
      ui2 v0 = {pk16(y0[0], y0[1]), pk16(y0[2], y0[3])};
      ui2 v1 = {pk16(y1[0], y1[1]), pk16(y1[2], y1[3])};
      *(ui2*)&s_ctil[r*520 + ct*4]       = v0;   // ctx_n cols ct*4..+3
      *(ui2*)&s_ctil[r*520 + 128 + ct*4] = v1;   // ctx_n cols 128+..
    }
  }
  // no barrier: ctx_n rows wave-local

  // ---- Phase E: out-right = ctx_n @ Wx^T ----
  {
    f32x4 eacc[4];
    #pragma unroll
    for (int rr = 0; rr < 4; ++rr) eacc[rr] = (f32x4){0,0,0,0};
    #pragma unroll 1
    for (int k0 = 0; k0 < 256; k0 += 8){
      ui4 a8[4];
      #pragma unroll
      for (int rr = 0; rr < 4; ++rr)
        a8[rr] = *(const ui4*)&s_ctil[(4*rt+rr)*520 + k0];
      #pragma unroll
      for (int kp = 0; kp < 4; ++kp){
        const ui4 w = ((const ui4*)(W3P + ((k0>>1) + kp)*128))[ct];
        #pragma unroll
        for (int rr = 0; rr < 4; ++rr){
          const h2 x = uph(a8[rr][kp]);
          #pragma unroll
          for (int j = 0; j < 4; ++j)
            eacc[rr][j] = FDOT2(x, uph(w[j]), eacc[rr][j]);
        }
      }
    }
    #pragma unroll
    for (int rr = 0; rr < 4; ++rr)
      *(f32x4*)&out[((long)(b0 + 4*rt + rr) << 8) + 128 + ct*4] = eacc[rr];
  }
}

extern "C" void kernel_launch(void* const* d_in, const int* in_sizes, int n_in,
                              void* d_out, int out_size, void* d_ws, size_t ws_size,
                              hipStream_t stream){
  const float* center = (const float*)d_in[0];
  const float* nbr    = (const float*)d_in[1];
  const float* ew     = (const float*)d_in[2];
  const float* Wq     = (const float*)d_in[3];
  const float* Wk     = (const float*)d_in[4];
  const float* Wv     = (const float*)d_in[5];
  const float* Wc     = (const float*)d_in[6];
  const float* Wx     = (const float*)d_in[7];
  const float* gamma  = (const float*)d_in[8];
  const float* beta   = (const float*)d_in[9];
  (void)in_sizes; (void)n_in; (void)out_size;

  unsigned int* W = (unsigned int*)d_ws;   // 512 KiB of workspace
  (void)ws_size;

  prep_kernel<<<1024, 256, 0, stream>>>(Wq, Wk, Wv, Wc, Wx, W);
  fused_kernel<<<Bsz/BR, 256, 0, stream>>>(center, nbr, ew, gamma, beta, W, (float*)d_out);
}

// Round 18
// 252.432 us; speedup vs baseline: 1.1913x; 1.1675x over previous
//
#include <hip/hip_runtime.h>

// B=32768, K=16, D=256, H=2, HD=128
#define Bsz 32768
#define BR  32           // rows per block; 8 rows per wave, wave-autonomous
#define SCALE 0.08838834764831845f   // 1/sqrt(128)

typedef __attribute__((ext_vector_type(4))) float f32x4;
typedef __attribute__((ext_vector_type(4))) unsigned short us4;
typedef __attribute__((ext_vector_type(8))) unsigned short us8;
typedef __attribute__((ext_vector_type(4))) unsigned int ui4;
typedef __attribute__((ext_vector_type(2))) unsigned int ui2;
typedef _Float16 __attribute__((ext_vector_type(2))) h2;
typedef _Float16 __attribute__((ext_vector_type(8))) h8;

static __device__ __forceinline__ unsigned int pk16(float a, float b){
  return __builtin_bit_cast(unsigned int, __builtin_amdgcn_cvt_pkrtz(a, b));
}
static __device__ __forceinline__ h2 uph(unsigned int u){
  return __builtin_bit_cast(h2, u);
}
static __device__ __forceinline__ float h2f(unsigned short h){
  return (float)__builtin_bit_cast(_Float16, h);
}
static __device__ __forceinline__ unsigned short f16b(float x){
  return __builtin_bit_cast(unsigned short, (_Float16)x);
}
static __device__ __forceinline__ h8 ldh8(const unsigned short* p){
  return __builtin_bit_cast(h8, *(const us8*)p);
}
#define FDOT2(a, b, c) __builtin_amdgcn_fdot2((a), (b), (c), false)
#define MFMA16(a, b, c) __builtin_amdgcn_mfma_f32_16x16x32_f16((a), (b), (c), 0, 0, 0)

// ---------------------------------------------------------------------------
// Prep (= round 12) + W1M: Wc row-major f16 [128][256] for the MFMA probe.
//   W1P uint [128][640]: cols 0..511 -> M_h[k][m] (h=n>>8,m=n&255); 512..639 Wc
//   W2P uint [128][256]: Wv^T packed;  W3P uint [128][128]: Wx^T packed
//   W1M us  [128][256] at uint offset 131072 (Wc rows, k-contiguous)
// ---------------------------------------------------------------------------
__global__ void prep_kernel(const float* __restrict__ Wq, const float* __restrict__ Wk,
                            const float* __restrict__ Wv, const float* __restrict__ Wc,
                            const float* __restrict__ Wx, unsigned int* __restrict__ wsp){
  unsigned int* W1P = wsp;                 // [128][640]
  unsigned int* W2P = wsp + 128*640;       // [128][256]
  unsigned int* W3P = W2P + 128*256;       // [128][128]
  unsigned short* W1M = (unsigned short*)(wsp + 131072);   // [128][256]
  const int n = blockIdx.x;
  const int k = threadIdx.x;
  float val;
  if (n < 512){
    const int h = n >> 8, m = n & 255;
    const float* wq = Wq + h*128*256 + k;
    const float* wk = Wk + h*128*256 + m;
    float s = 0.f;
    for (int d = 0; d < 128; ++d) s += wq[d*256] * wk[d*256];
    val = s;
  } else if (n < 640){
    val = Wc[(n-512)*256 + k];
  } else if (n < 896){
    val = Wv[(n-640)*256 + k];
  } else {
    val = Wx[(n-896)*256 + k];
  }
  if (n >= 512 && n < 640) W1M[(n-512)*256 + k] = f16b(val);
  const float vo = __shfl_xor(val, 1, 64);
  if ((k & 1) == 0){
    const unsigned int p = pk16(val, vo);
    const int kp = k >> 1;
    if (n < 640)      W1P[kp*640 + n] = p;
    else if (n < 896) W2P[kp*256 + (n-640)] = p;
    else              W3P[kp*128 + (n-896)] = p;
  }
}

// ---------------------------------------------------------------------------
// Fused kernel = round 12 verbatim EXCEPT: out-left computed via MFMA
// (bisect probe; Wc row-major f16 B-fragments), fdot2 pass 1 drops tile 4.
// Two barriers added around the MFMA section (wave-pairs share 16-row
// center tiles); all other phases remain zero-barrier wave-autonomous.
// ---------------------------------------------------------------------------
__global__ __launch_bounds__(256, 4) void fused_kernel(
    const float* __restrict__ center, const float* __restrict__ nbr,
    const float* __restrict__ ew, const float* __restrict__ gamma,
    const float* __restrict__ beta, const unsigned int* __restrict__ Wall,
    float* __restrict__ out)
{
  __shared__ __align__(16) unsigned short s_ctil[BR*520];

  const int tid  = threadIdx.x;
  const int wid  = tid >> 6;
  const int lane = tid & 63;
  const int b0   = blockIdx.x * BR;

  const unsigned int* W1P = Wall;               // [128][640]
  const unsigned int* W2P = Wall + 128*640;     // [128][256]
  const unsigned int* W3P = W2P + 128*256;      // [128][128]
  const unsigned short* W1M = (const unsigned short*)(Wall + 131072);  // [128][256]

  const int rt = tid >> 5;     // 0..7  (rows 4rt..4rt+3)
  const int ct = tid & 31;     // 0..31 (col quad)

  // ---- stage center rows 8w..8w+7 as packed f16 pairs -> cells 256..511 ----
  {
    const int sr = tid >> 3;            // 0..31, wave-local rows
    const int fc = (tid & 7) * 32;      // float col base
    const float* cp = center + ((long)(b0 + sr) << 8) + fc;
    #pragma unroll
    for (int it = 0; it < 4; ++it){
      float4 a = *(const float4*)(cp + it*8);
      float4 b = *(const float4*)(cp + it*8 + 4);
      ui4 v = {pk16(a.x,a.y), pk16(a.z,a.w), pk16(b.x,b.y), pk16(b.z,b.w)};
      *(ui4*)&s_ctil[sr*520 + 256 + fc + it*8] = v;
    }
  }
  __syncthreads();   // MFMA section reads center rows across the wave pair

  // ---- out-left via MFMA (BISECT PROBE): [32x256] @ [256x128] ----
  {
    const int rowg = wid >> 1;       // 16-row group
    const int colq = wid & 1;        // 64-col half
    const int l15 = lane & 15, lq = lane >> 4;
    h8 af[8];
    #pragma unroll
    for (int kk = 0; kk < 8; ++kk)
      af[kk] = __builtin_bit_cast(h8,
        *(const us8*)&s_ctil[(rowg*16 + l15)*520 + 256 + kk*32 + lq*8]);
    f32x4 macc[4];
    #pragma unroll
    for (int t = 0; t < 4; ++t) macc[t] = (f32x4){0,0,0,0};
    #pragma unroll
    for (int kk = 0; kk < 8; ++kk)
      #pragma unroll
      for (int t = 0; t < 4; ++t){
        const int col = colq*64 + t*16 + l15;      // 0..127
        macc[t] = MFMA16(af[kk], ldh8(W1M + col*256 + kk*32 + lq*8), macc[t]);
      }
    #pragma unroll
    for (int t = 0; t < 4; ++t)
      #pragma unroll
      for (int j = 0; j < 4; ++j)
        out[((long)(b0 + rowg*16 + lq*4 + j) << 8) + colq*64 + t*16 + l15] = macc[t][j];
  }
  __syncthreads();   // protect center cells from pass-2 overwrite below

  // ---- Phase A pass 1: tiles {0,1} -> ctil cols 0..255 ----
  {
    f32x4 acc[4][2];
    #pragma unroll
    for (int rr = 0; rr < 4; ++rr){ acc[rr][0] = (f32x4){0,0,0,0}; acc[rr][1] = (f32x4){0,0,0,0}; }
    #pragma unroll 1
    for (int k0 = 0; k0 < 256; k0 += 8){
      ui4 a8[4];
      #pragma unroll
      for (int rr = 0; rr < 4; ++rr)
        a8[rr] = *(const ui4*)&s_ctil[(4*rt+rr)*520 + 256 + k0];
      #pragma unroll
      for (int kp = 0; kp < 4; ++kp){
        const unsigned int* wrow = W1P + ((k0>>1) + kp)*640;
        const ui4 w0 = ((const ui4*)(wrow      ))[ct];
        const ui4 w1 = ((const ui4*)(wrow + 128))[ct];
        #pragma unroll
        for (int rr = 0; rr < 4; ++rr){
          const h2 a2 = uph(a8[rr][kp]);
          #pragma unroll
          for (int j = 0; j < 4; ++j){
            acc[rr][0][j] = FDOT2(a2, uph(w0[j]), acc[rr][0][j]);
            acc[rr][1][j] = FDOT2(a2, uph(w1[j]), acc[rr][1][j]);
          }
        }
      }
    }
    #pragma unroll
    for (int rr = 0; rr < 4; ++rr){
      const int r = 4*rt + rr;
      ui2 v0 = {pk16(acc[rr][0][0], acc[rr][0][1]), pk16(acc[rr][0][2], acc[rr][0][3])};
      ui2 v1 = {pk16(acc[rr][1][0], acc[rr][1][1]), pk16(acc[rr][1][2], acc[rr][1][3])};
      *(ui2*)&s_ctil[r*520 + ct*4]       = v0;    // ctil cols ct*4..+3
      *(ui2*)&s_ctil[r*520 + 128 + ct*4] = v1;    // ctil cols 128+..
    }
  }

  // ---- Phase A pass 2: tiles {2,3} -> ctil cols 256..511 (post-loop write) ----
  {
    f32x4 acc[4][2];
    #pragma unroll
    for (int rr = 0; rr < 4; ++rr){ acc[rr][0] = (f32x4){0,0,0,0}; acc[rr][1] = (f32x4){0,0,0,0}; }
    #pragma unroll 1
    for (int k0 = 0; k0 < 256; k0 += 8){
      ui4 a8[4];
      #pragma unroll
      for (int rr = 0; rr < 4; ++rr)
        a8[rr] = *(const ui4*)&s_ctil[(4*rt+rr)*520 + 256 + k0];
      #pragma unroll
      for (int kp = 0; kp < 4; ++kp){
        const unsigned int* wrow = W1P + ((k0>>1) + kp)*640;
        const ui4 w2 = ((const ui4*)(wrow + 256))[ct];
        const ui4 w3 = ((const ui4*)(wrow + 384))[ct];
        #pragma unroll
        for (int rr = 0; rr < 4; ++rr){
          const h2 a2 = uph(a8[rr][kp]);
          #pragma unroll
          for (int j = 0; j < 4; ++j){
            acc[rr][0][j] = FDOT2(a2, uph(w2[j]), acc[rr][0][j]);
            acc[rr][1][j] = FDOT2(a2, uph(w3[j]), acc[rr][1][j]);
          }
        }
      }
    }
    // all center reads done (both passes + MFMA barrier); overwrite is wave-local
    #pragma unroll
    for (int rr = 0; rr < 4; ++rr){
      const int r = 4*rt + rr;
      ui2 v0 = {pk16(acc[rr][0][0], acc[rr][0][1]), pk16(acc[rr][0][2], acc[rr][0][3])};
      ui2 v1 = {pk16(acc[rr][1][0], acc[rr][1][1]), pk16(acc[rr][1][2], acc[rr][1][3])};
      *(ui2*)&s_ctil[r*520 + 256 + ct*4] = v0;    // ctil cols 256+..
      *(ui2*)&s_ctil[r*520 + 384 + ct*4] = v1;    // ctil cols 384+..
    }
  }
  // no barrier: ctil rows wave-local

  // ---- Phase B: attention, 8 rows/wave; reduce-scatter scores ----
  {
    const int myk = ((lane>>4)&1)*8 + ((lane>>3)&1)*4 + ((lane>>2)&1)*2 + ((lane>>1)&1);
    const int myh = lane >> 5;
    #pragma unroll 1
    for (int rr = 0; rr < 8; ++rr){
      const int r = wid*8 + rr;
      const long b = b0 + r;
      float4 c0, c1;
      {
        us4 h0 = *(const us4*)&s_ctil[r*520 + lane*4];
        us4 h1 = *(const us4*)&s_ctil[r*520 + 256 + lane*4];
        c0.x=h2f(h0[0]); c0.y=h2f(h0[1]); c0.z=h2f(h0[2]); c0.w=h2f(h0[3]);
        c1.x=h2f(h1[0]); c1.y=h2f(h1[1]); c1.z=h2f(h1[2]); c1.w=h2f(h1[3]);
      }
      float4 xv[16];
      const float* npt = nbr + ((b << 4) << 8) + lane*4;
      #pragma unroll
      for (int k = 0; k < 16; ++k) xv[k] = *(const float4*)(npt + (k << 8));
      float P0[16], P1[16];
      #pragma unroll
      for (int k = 0; k < 16; ++k){
        P0[k] = xv[k].x*c0.x + xv[k].y*c0.y + xv[k].z*c0.z + xv[k].w*c0.w;
        P1[k] = xv[k].x*c1.x + xv[k].y*c1.y + xv[k].z*c1.z + xv[k].w*c1.w;
      }
      // reduce-scatter: masks 32,16,8,4,2, then final 1
      const int b5 = lane & 32, b4 = lane & 16, b3 = lane & 8, b2 = lane & 4, b1 = lane & 2;
      float Q[16];
      #pragma unroll
      for (int j = 0; j < 16; ++j){
        const float give = b5 ? P0[j] : P1[j];
        const float keep = b5 ? P1[j] : P0[j];
        Q[j] = keep + __shfl_xor(give, 32, 64);
      }
      float R[8];
      #pragma unroll
      for (int j = 0; j < 8; ++j){
        const float give = b4 ? Q[j] : Q[8+j];
        const float keep = b4 ? Q[8+j] : Q[j];
        R[j] = keep + __shfl_xor(give, 16, 64);
      }
      float S[4];
      #pragma unroll
      for (int j = 0; j < 4; ++j){
        const float give = b3 ? R[j] : R[4+j];
        const float keep = b3 ? R[4+j] : R[j];
        S[j] = keep + __shfl_xor(give, 8, 64);
      }
      float T[2];
      #pragma unroll
      for (int j = 0; j < 2; ++j){
        const float give = b2 ? S[j] : S[2+j];
        const float keep = b2 ? S[2+j] : S[j];
        T[j] = keep + __shfl_xor(give, 4, 64);
      }
      float U;
      {
        const float give = b1 ? T[0] : T[1];
        const float keep = b1 ? T[1] : T[0];
        U = keep + __shfl_xor(give, 2, 64);
      }
      const float sfull = U + __shfl_xor(U, 1, 64);   // s[myh][myk]
      const float erk = ew[b*16 + myk];
      const float e = __expf(sfull*SCALE + erk);      // scores O(1): no max-sub
      float dn = e;
      dn += __shfl_xor(dn, 2, 64);
      dn += __shfl_xor(dn, 4, 64);
      dn += __shfl_xor(dn, 8, 64);
      dn += __shfl_xor(dn, 16, 64);
      const float w = e / dn;
      // broadcast via wave-local overlay of head1-ctil cells (c1 already read)
      float* wbuf = (float*)&s_ctil[r*520 + 256];
      wbuf[myh*16 + myk] = w;                         // 2 lanes same addr, same value
      f32x4 wv[8];
      #pragma unroll
      for (int t = 0; t < 8; ++t) wv[t] = ((const f32x4*)wbuf)[t];
      float4 agg0 = {0,0,0,0}, agg1 = {0,0,0,0};
      #pragma unroll
      for (int k = 0; k < 16; ++k){
        const float w0 = wv[k>>2][k&3];
        const float w1 = wv[4 + (k>>2)][k&3];
        agg0.x += w0*xv[k].x; agg0.y += w0*xv[k].y; agg0.z += w0*xv[k].z; agg0.w += w0*xv[k].w;
        agg1.x += w1*xv[k].x; agg1.y += w1*xv[k].y; agg1.z += w1*xv[k].z; agg1.w += w1*xv[k].w;
      }
      ui2 v0 = {pk16(agg0.x, agg0.y), pk16(agg0.z, agg0.w)};
      ui2 v1 = {pk16(agg1.x, agg1.y), pk16(agg1.z, agg1.w)};
      *(ui2*)&s_ctil[r*520 + lane*4]       = v0;   // agg0 (WAR on own cells)
      *(ui2*)&s_ctil[r*520 + 256 + lane*4] = v1;   // agg1 (overwrites wbuf after read)
    }
  }
  // no barrier: agg rows wave-local

  // ---- Phase C (+fused LayerNorm): ctx in registers -> ctx_n packed f16 ----
  {
    f32x4 cacc[4][2];
    #pragma unroll
    for (int rr = 0; rr < 4; ++rr){ cacc[rr][0] = (f32x4){0,0,0,0}; cacc[rr][1] = (f32x4){0,0,0,0}; }
    #pragma unroll 1
    for (int k0 = 0; k0 < 256; k0 += 8){
      ui4 a0[4], a1[4];
      #pragma unroll
      for (int rr = 0; rr < 4; ++rr){
        a0[rr] = *(const ui4*)&s_ctil[(4*rt+rr)*520 + k0];
        a1[rr] = *(const ui4*)&s_ctil[(4*rt+rr)*520 + 256 + k0];
      }
      #pragma unroll
      for (int kp = 0; kp < 4; ++kp){
        const unsigned int* wrow = W2P + ((k0>>1) + kp)*256;
        const ui4 w0 = ((const ui4*)(wrow      ))[ct];   // ctx cols 0..127 (head0)
        const ui4 w1 = ((const ui4*)(wrow + 128))[ct];   // ctx cols 128..255 (head1)
        #pragma unroll
        for (int rr = 0; rr < 4; ++rr){
          const h2 x0 = uph(a0[rr][kp]);
          const h2 x1 = uph(a1[rr][kp]);
          #pragma unroll
          for (int j = 0; j < 4; ++j){
            cacc[rr][0][j] = FDOT2(x0, uph(w0[j]), cacc[rr][0][j]);
            cacc[rr][1][j] = FDOT2(x1, uph(w1[j]), cacc[rr][1][j]);
          }
        }
      }
    }
    // fused LayerNorm across the 32 ct-lanes of each rt group
    const f32x4 gv0 = ((const f32x4*)gamma)[ct], gv1 = ((const f32x4*)gamma)[32 + ct];
    const f32x4 bv0 = ((const f32x4*)beta )[ct], bv1 = ((const f32x4*)beta )[32 + ct];
    #pragma unroll
    for (int rr = 0; rr < 4; ++rr){
      float s = 0.f, q = 0.f;
      #pragma unroll
      for (int t = 0; t < 2; ++t)
        #pragma unroll
        for (int j = 0; j < 4; ++j){
          const float x = cacc[rr][t][j];
          s += x; q += x*x;
        }
      #pragma unroll
      for (int m = 16; m >= 1; m >>= 1){
        s += __shfl_xor(s, m, 64);
        q += __shfl_xor(q, m, 64);
      }
      const float mu  = s * (1.f/256.f);
      const float var = q * (1.f/256.f) - mu*mu;
      const float rs  = rsqrtf(var + 1e-5f);
      const int r = 4*rt + rr;
      float y0[4], y1[4];
      #pragma unroll
      for (int j = 0; j < 4; ++j){
        y0[j] = (cacc[rr][0][j] - mu)*rs*gv0[j] + bv0[j];
        y1[j] = (cacc[rr][1][j] - mu)*rs*gv1[j] + bv1[j];
      }
      ui2 v0 = {pk16(y0[0], y0[1]), pk16(y0[2], y0[3])};
      ui2 v1 = {pk16(y1[0], y1[1]), pk16(y1[2], y1[3])};
      *(ui2*)&s_ctil[r*520 + ct*4]       = v0;   // ctx_n cols ct*4..+3
      *(ui2*)&s_ctil[r*520 + 128 + ct*4] = v1;   // ctx_n cols 128+..
    }
  }
  // no barrier: ctx_n rows wave-local

  // ---- Phase E: out-right = ctx_n @ Wx^T ----
  {
    f32x4 eacc[4];
    #pragma unroll
    for (int rr = 0; rr < 4; ++rr) eacc[rr] = (f32x4){0,0,0,0};
    #pragma unroll 1
    for (int k0 = 0; k0 < 256; k0 += 8){
      ui4 a8[4];
      #pragma unroll
      for (int rr = 0; rr < 4; ++rr)
        a8[rr] = *(const ui4*)&s_ctil[(4*rt+rr)*520 + k0];
      #pragma unroll
      for (int kp = 0; kp < 4; ++kp){
        const ui4 w = ((const ui4*)(W3P + ((k0>>1) + kp)*128))[ct];
        #pragma unroll
        for (int rr = 0; rr < 4; ++rr){
          const h2 x = uph(a8[rr][kp]);
          #pragma unroll
          for (int j = 0; j < 4; ++j)
            eacc[rr][j] = FDOT2(x, uph(w[j]), eacc[rr][j]);
        }
      }
    }
    #pragma unroll
    for (int rr = 0; rr < 4; ++rr)
      *(f32x4*)&out[((long)(b0 + 4*rt + rr) << 8) + 128 + ct*4] = eacc[rr];
  }
}

extern "C" void kernel_launch(void* const* d_in, const int* in_sizes, int n_in,
                              void* d_out, int out_size, void* d_ws, size_t ws_size,
                              hipStream_t stream){
  const float* center = (const float*)d_in[0];
  const float* nbr    = (const float*)d_in[1];
  const float* ew     = (const float*)d_in[2];
  const float* Wq     = (const float*)d_in[3];
  const float* Wk     = (const float*)d_in[4];
  const float* Wv     = (const float*)d_in[5];
  const float* Wc     = (const float*)d_in[6];
  const float* Wx     = (const float*)d_in[7];
  const float* gamma  = (const float*)d_in[8];
  const float* beta   = (const float*)d_in[9];
  (void)in_sizes; (void)n_in; (void)out_size;

  unsigned int* W = (unsigned int*)d_ws;   // 512 KiB packed + 64 KiB W1M
  (void)ws_size;

  prep_kernel<<<1024, 256, 0, stream>>>(Wq, Wk, Wv, Wc, Wx, W);
  fused_kernel<<<Bsz/BR, 256, 0, stream>>>(center, nbr, ew, gamma, beta, W, (float*)d_out);
}

// Round 19
// 219.276 us; speedup vs baseline: 1.3714x; 1.1512x over previous
//
#include <hip/hip_runtime.h>

// B=32768, K=16, D=256, H=2, HD=128
#define Bsz 32768
#define BR  32           // rows per block; wave-autonomous after phase A
#define SCALE 0.08838834764831845f   // 1/sqrt(128)

typedef __attribute__((ext_vector_type(4))) float f32x4;
typedef __attribute__((ext_vector_type(4))) unsigned short us4;
typedef __attribute__((ext_vector_type(8))) unsigned short us8;
typedef __attribute__((ext_vector_type(4))) unsigned int ui4;
typedef __attribute__((ext_vector_type(2))) unsigned int ui2;
typedef _Float16 __attribute__((ext_vector_type(2))) h2;
typedef _Float16 __attribute__((ext_vector_type(8))) h8;

static __device__ __forceinline__ unsigned int pk16(float a, float b){
  return __builtin_bit_cast(unsigned int, __builtin_amdgcn_cvt_pkrtz(a, b));
}
static __device__ __forceinline__ h2 uph(unsigned int u){
  return __builtin_bit_cast(h2, u);
}
static __device__ __forceinline__ float h2f(unsigned short h){
  return (float)__builtin_bit_cast(_Float16, h);
}
static __device__ __forceinline__ unsigned short f16b(float x){
  return __builtin_bit_cast(unsigned short, (_Float16)x);
}
static __device__ __forceinline__ h8 ldh8(const unsigned short* p){
  return __builtin_bit_cast(h8, *(const us8*)p);
}
#define FDOT2(a, b, c) __builtin_amdgcn_fdot2((a), (b), (c), false)
#define MFMA16(a, b, c) __builtin_amdgcn_mfma_f32_16x16x32_f16((a), (b), (c), 0, 0, 0)

// ---------------------------------------------------------------------------
// Prep: W1 ROW-MAJOR f16 (MFMA B-fragments); W2/W3 k-pair packed (fdot2).
//   W1R us  [640][256]: rows 0..511 -> M_h[.][m]: W1R[n][k] = M row n elem k
//                       (n=h*256+m); rows 512..639 -> Wc
//   W2P uint [128][256]: Wv^T packed;  W3P uint [128][128]: Wx^T packed
// ws total: 327680 + 131072 + 65536 = 512 KiB.
// ---------------------------------------------------------------------------
__global__ void prep_kernel(const float* __restrict__ Wq, const float* __restrict__ Wk,
                            const float* __restrict__ Wv, const float* __restrict__ Wc,
                            const float* __restrict__ Wx, unsigned short* __restrict__ wsp){
  unsigned short* W1R = wsp;                                   // [640][256]
  unsigned int*   W2P = (unsigned int*)(wsp + 640*256);        // [128][256]
  unsigned int*   W3P = W2P + 128*256;                         // [128][128]
  const int n = blockIdx.x;
  const int k = threadIdx.x;
  float val;
  if (n < 512){
    const int h = n >> 8, m = n & 255;
    const float* wq = Wq + h*128*256 + k;
    const float* wk = Wk + h*128*256 + m;
    float s = 0.f;
    for (int d = 0; d < 128; ++d) s += wq[d*256] * wk[d*256];
    val = s;
  } else if (n < 640){
    val = Wc[(n-512)*256 + k];
  } else if (n < 896){
    val = Wv[(n-640)*256 + k];
  } else {
    val = Wx[(n-896)*256 + k];
  }
  if (n < 640){
    W1R[n*256 + k] = f16b(val);
  } else {
    const float vo = __shfl_xor(val, 1, 64);
    if ((k & 1) == 0){
      const unsigned int p = pk16(val, vo);
      const int kp = k >> 1;
      if (n < 896) W2P[kp*256 + (n-640)] = p;
      else         W3P[kp*128 + (n-896)] = p;
    }
  }
}

// ---------------------------------------------------------------------------
// Fused kernel. Phase A (ctil + out-left) fully via MFMA (validated by the
// round-18 probe); phases B/C/LN/E verbatim round 12 (fdot2, zero barriers,
// wave w owns rows 8w..8w+7). Barriers: stage|afload, afload|Awrite, A|B.
// Wave roles in A: rowg=wid>>1 (16-row half), colh=wid&1 (20-tile column
// half: colh*20 + 0..19; tiles 0..31 -> ctil, 32..39 -> out-left).
// LDS s_ctil us[32][520]: center f16 (cells 256..511, stage..afload) ->
//   ctil cols 0..511 (A..B) -> wbuf+agg (B..C) -> ctx_n (C..E)  [R12 map]
// ---------------------------------------------------------------------------
__global__ __launch_bounds__(256, 4) void fused_kernel(
    const float* __restrict__ center, const float* __restrict__ nbr,
    const float* __restrict__ ew, const float* __restrict__ gamma,
    const float* __restrict__ beta, const unsigned short* __restrict__ Wall,
    float* __restrict__ out)
{
  __shared__ __align__(16) unsigned short s_ctil[BR*520];

  const int tid  = threadIdx.x;
  const int wid  = tid >> 6;
  const int lane = tid & 63;
  const int b0   = blockIdx.x * BR;

  const unsigned short* W1R = Wall;                                // [640][256]
  const unsigned int*   W2P = (const unsigned int*)(Wall + 640*256); // [128][256]
  const unsigned int*   W3P = W2P + 128*256;                         // [128][128]

  const int rt = tid >> 5;     // 0..7  (rows 4rt..4rt+3; C/E fdot2 map)
  const int ct = tid & 31;     // 0..31 (col quad; C/E fdot2 map)

  // ---- stage center rows 8w..8w+7 as f16 -> cells 256..511 (R12/R18) ----
  {
    const int sr = tid >> 3;            // 0..31, wave-local rows
    const int fc = (tid & 7) * 32;      // f16 col base
    const float* cp = center + ((long)(b0 + sr) << 8) + fc;
    #pragma unroll
    for (int it = 0; it < 4; ++it){
      float4 a = *(const float4*)(cp + it*8);
      float4 b = *(const float4*)(cp + it*8 + 4);
      ui4 v = {pk16(a.x,a.y), pk16(a.z,a.w), pk16(b.x,b.y), pk16(b.z,b.w)};
      *(ui4*)&s_ctil[sr*520 + 256 + fc + it*8] = v;
    }
  }
  __syncthreads();

  // ---- Phase A via MFMA: [32x256]@[256x640] -> ctil (LDS) + out-left ----
  {
    const int rowg = wid >> 1;       // 16-row group
    const int colh = wid & 1;        // 20-tile column half
    const int l15 = lane & 15, lq = lane >> 4;
    h8 af[8];
    #pragma unroll
    for (int kk = 0; kk < 8; ++kk)
      af[kk] = __builtin_bit_cast(h8,
        *(const us8*)&s_ctil[(rowg*16 + l15)*520 + 256 + kk*32 + lq*8]);
    __syncthreads();   // all fragment loads done before ctil overwrites cells 256+
    #pragma unroll 1
    for (int c0t = 0; c0t < 20; c0t += 5){
      f32x4 acc[5];
      #pragma unroll
      for (int u = 0; u < 5; ++u) acc[u] = (f32x4){0,0,0,0};
      #pragma unroll
      for (int kk = 0; kk < 8; ++kk)
        #pragma unroll
        for (int u = 0; u < 5; ++u){
          const int gt = colh*20 + c0t + u;
          acc[u] = MFMA16(af[kk], ldh8(W1R + (gt*16 + l15)*256 + kk*32 + lq*8), acc[u]);
        }
      #pragma unroll
      for (int u = 0; u < 5; ++u){
        const int gt = colh*20 + c0t + u;
        if (gt < 32){
          #pragma unroll
          for (int j = 0; j < 4; ++j)
            s_ctil[(rowg*16 + lq*4 + j)*520 + gt*16 + l15] = f16b(acc[u][j]);
        } else {
          #pragma unroll
          for (int j = 0; j < 4; ++j)
            out[((long)(b0 + rowg*16 + lq*4 + j) << 8) + (gt-32)*16 + l15] = acc[u][j];
        }
      }
    }
  }
  __syncthreads();

  // ---- Phase B: attention (VERBATIM round 12), 8 rows/wave ----
  {
    const int myk = ((lane>>4)&1)*8 + ((lane>>3)&1)*4 + ((lane>>2)&1)*2 + ((lane>>1)&1);
    const int myh = lane >> 5;
    #pragma unroll 1
    for (int rr = 0; rr < 8; ++rr){
      const int r = wid*8 + rr;
      const long b = b0 + r;
      float4 c0, c1;
      {
        us4 h0 = *(const us4*)&s_ctil[r*520 + lane*4];
        us4 h1 = *(const us4*)&s_ctil[r*520 + 256 + lane*4];
        c0.x=h2f(h0[0]); c0.y=h2f(h0[1]); c0.z=h2f(h0[2]); c0.w=h2f(h0[3]);
        c1.x=h2f(h1[0]); c1.y=h2f(h1[1]); c1.z=h2f(h1[2]); c1.w=h2f(h1[3]);
      }
      float4 xv[16];
      const float* npt = nbr + ((b << 4) << 8) + lane*4;
      #pragma unroll
      for (int k = 0; k < 16; ++k) xv[k] = *(const float4*)(npt + (k << 8));
      float P0[16], P1[16];
      #pragma unroll
      for (int k = 0; k < 16; ++k){
        P0[k] = xv[k].x*c0.x + xv[k].y*c0.y + xv[k].z*c0.z + xv[k].w*c0.w;
        P1[k] = xv[k].x*c1.x + xv[k].y*c1.y + xv[k].z*c1.z + xv[k].w*c1.w;
      }
      // reduce-scatter: masks 32,16,8,4,2, then final 1
      const int b5 = lane & 32, b4 = lane & 16, b3 = lane & 8, b2 = lane & 4, b1 = lane & 2;
      float Q[16];
      #pragma unroll
      for (int j = 0; j < 16; ++j){
        const float give = b5 ? P0[j] : P1[j];
        const float keep = b5 ? P1[j] : P0[j];
        Q[j] = keep + __shfl_xor(give, 32, 64);
      }
      float R[8];
      #pragma unroll
      for (int j = 0; j < 8; ++j){
        const float give = b4 ? Q[j] : Q[8+j];
        const float keep = b4 ? Q[8+j] : Q[j];
        R[j] = keep + __shfl_xor(give, 16, 64);
      }
      float S[4];
      #pragma unroll
      for (int j = 0; j < 4; ++j){
        const float give = b3 ? R[j] : R[4+j];
        const float keep = b3 ? R[4+j] : R[j];
        S[j] = keep + __shfl_xor(give, 8, 64);
      }
      float T[2];
      #pragma unroll
      for (int j = 0; j < 2; ++j){
        const float give = b2 ? S[j] : S[2+j];
        const float keep = b2 ? S[2+j] : S[j];
        T[j] = keep + __shfl_xor(give, 4, 64);
      }
      float U;
      {
        const float give = b1 ? T[0] : T[1];
        const float keep = b1 ? T[1] : T[0];
        U = keep + __shfl_xor(give, 2, 64);
      }
      const float sfull = U + __shfl_xor(U, 1, 64);   // s[myh][myk]
      const float erk = ew[b*16 + myk];
      const float e = __expf(sfull*SCALE + erk);      // scores O(1): no max-sub
      float dn = e;
      dn += __shfl_xor(dn, 2, 64);
      dn += __shfl_xor(dn, 4, 64);
      dn += __shfl_xor(dn, 8, 64);
      dn += __shfl_xor(dn, 16, 64);
      const float w = e / dn;
      // broadcast via wave-local overlay of head1-ctil cells (c1 already read)
      float* wbuf = (float*)&s_ctil[r*520 + 256];
      wbuf[myh*16 + myk] = w;                         // 2 lanes same addr, same value
      f32x4 wv[8];
      #pragma unroll
      for (int t = 0; t < 8; ++t) wv[t] = ((const f32x4*)wbuf)[t];
      float4 agg0 = {0,0,0,0}, agg1 = {0,0,0,0};
      #pragma unroll
      for (int k = 0; k < 16; ++k){
        const float w0 = wv[k>>2][k&3];
        const float w1 = wv[4 + (k>>2)][k&3];
        agg0.x += w0*xv[k].x; agg0.y += w0*xv[k].y; agg0.z += w0*xv[k].z; agg0.w += w0*xv[k].w;
        agg1.x += w1*xv[k].x; agg1.y += w1*xv[k].y; agg1.z += w1*xv[k].z; agg1.w += w1*xv[k].w;
      }
      ui2 v0 = {pk16(agg0.x, agg0.y), pk16(agg0.z, agg0.w)};
      ui2 v1 = {pk16(agg1.x, agg1.y), pk16(agg1.z, agg1.w)};
      *(ui2*)&s_ctil[r*520 + lane*4]       = v0;   // agg0 (WAR on own cells)
      *(ui2*)&s_ctil[r*520 + 256 + lane*4] = v1;   // agg1 (overwrites wbuf after read)
    }
  }
  // no barrier: agg rows wave-local

  // ---- Phase C (+fused LayerNorm): ctx in registers -> ctx_n packed f16 ----
  {
    f32x4 cacc[4][2];
    #pragma unroll
    for (int rr = 0; rr < 4; ++rr){ cacc[rr][0] = (f32x4){0,0,0,0}; cacc[rr][1] = (f32x4){0,0,0,0}; }
    #pragma unroll 1
    for (int k0 = 0; k0 < 256; k0 += 8){
      ui4 a0[4], a1[4];
      #pragma unroll
      for (int rr = 0; rr < 4; ++rr){
        a0[rr] = *(const ui4*)&s_ctil[(4*rt+rr)*520 + k0];
        a1[rr] = *(const ui4*)&s_ctil[(4*rt+rr)*520 + 256 + k0];
      }
      #pragma unroll
      for (int kp = 0; kp < 4; ++kp){
        const unsigned int* wrow = W2P + ((k0>>1) + kp)*256;
        const ui4 w0 = ((const ui4*)(wrow      ))[ct];   // ctx cols 0..127 (head0)
        const ui4 w1 = ((const ui4*)(wrow + 128))[ct];   // ctx cols 128..255 (head1)
        #pragma unroll
        for (int rr = 0; rr < 4; ++rr){
          const h2 x0 = uph(a0[rr][kp]);
          const h2 x1 = uph(a1[rr][kp]);
          #pragma unroll
          for (int j = 0; j < 4; ++j){
            cacc[rr][0][j] = FDOT2(x0, uph(w0[j]), cacc[rr][0][j]);
            cacc[rr][1][j] = FDOT2(x1, uph(w1[j]), cacc[rr][1][j]);
          }
        }
      }
    }
    // fused LayerNorm across the 32 ct-lanes of each rt group
    const f32x4 gv0 = ((const f32x4*)gamma)[ct], gv1 = ((const f32x4*)gamma)[32 + ct];
    const f32x4 bv0 = ((const f32x4*)beta )[ct], bv1 = ((const f32x4*)beta )[32 + ct];
    #pragma unroll
    for (int rr = 0; rr < 4; ++rr){
      float s = 0.f, q = 0.f;
      #pragma unroll
      for (int t = 0; t < 2; ++t)
        #pragma unroll
        for (int j = 0; j < 4; ++j){
          const float x = cacc[rr][t][j];
          s += x; q += x*x;
        }
      #pragma unroll
      for (int m = 16; m >= 1; m >>= 1){
        s += __shfl_xor(s, m, 64);
        q += __shfl_xor(q, m, 64);
      }
      const float mu  = s * (1.f/256.f);
      const float var = q * (1.f/256.f) - mu*mu;
      const float rs  = rsqrtf(var + 1e-5f);
      const int r = 4*rt + rr;
      float y0[4], y1[4];
      #pragma unroll
      for (int j = 0; j < 4; ++j){
        y0[j] = (cacc[rr][0][j] - mu)*rs*gv0[j] + bv0[j];
        y1[j] = (cacc[rr][1][j] - mu)*rs*gv1[j] + bv1[j];
      }
      ui2 v0 = {pk16(y0[0], y0[1]), pk16(y0[2], y0[3])};
      ui2 v1 = {pk16(y1[0], y1[1]), pk16(y1[2], y1[3])};
      *(ui2*)&s_ctil[r*520 + ct*4]       = v0;   // ctx_n cols ct*4..+3
      *(ui2*)&s_ctil[r*520 + 128 + ct*4] = v1;   // ctx_n cols 128+..
    }
  }
  // no barrier: ctx_n rows wave-local

  // ---- Phase E: out-right = ctx_n @ Wx^T ----
  {
    f32x4 eacc[4];
    #pragma unroll
    for (int rr = 0; rr < 4; ++rr) eacc[rr] = (f32x4){0,0,0,0};
    #pragma unroll 1
    for (int k0 = 0; k0 < 256; k0 += 8){
      ui4 a8[4];
      #pragma unroll
      for (int rr = 0; rr < 4; ++rr)
        a8[rr] = *(const ui4*)&s_ctil[(4*rt+rr)*520 + k0];
      #pragma unroll
      for (int kp = 0; kp < 4; ++kp){
        const ui4 w = ((const ui4*)(W3P + ((k0>>1) + kp)*128))[ct];
        #pragma unroll
        for (int rr = 0; rr < 4; ++rr){
          const h2 x = uph(a8[rr][kp]);
          #pragma unroll
          for (int j = 0; j < 4; ++j)
            eacc[rr][j] = FDOT2(x, uph(w[j]), eacc[rr][j]);
        }
      }
    }
    #pragma unroll
    for (int rr = 0; rr < 4; ++rr)
      *(f32x4*)&out[((long)(b0 + 4*rt + rr) << 8) + 128 + ct*4] = eacc[rr];
  }
}

extern "C" void kernel_launch(void* const* d_in, const int* in_sizes, int n_in,
                              void* d_out, int out_size, void* d_ws, size_t ws_size,
                              hipStream_t stream){
  const float* center = (const float*)d_in[0];
  const float* nbr    = (const float*)d_in[1];
  const float* ew     = (const float*)d_in[2];
  const float* Wq     = (const float*)d_in[3];
  const float* Wk     = (const float*)d_in[4];
  const float* Wv     = (const float*)d_in[5];
  const float* Wc     = (const float*)d_in[6];
  const float* Wx     = (const float*)d_in[7];
  const float* gamma  = (const float*)d_in[8];
  const float* beta   = (const float*)d_in[9];
  (void)in_sizes; (void)n_in; (void)out_size;

  unsigned short* W = (unsigned short*)d_ws;   // 512 KiB of workspace
  (void)ws_size;

  prep_kernel<<<1024, 256, 0, stream>>>(Wq, Wk, Wv, Wc, Wx, W);
  fused_kernel<<<Bsz/BR, 256, 0, stream>>>(center, nbr, ew, gamma, beta, W, (float*)d_out);
}

// Round 20
// 212.403 us; speedup vs baseline: 1.4158x; 1.0324x over previous
//
#include <hip/hip_runtime.h>

// B=32768, K=16, D=256, H=2, HD=128
#define Bsz 32768
#define BR  32           // rows per block
#define SCALE 0.08838834764831845f   // 1/sqrt(128)

typedef __attribute__((ext_vector_type(4))) float f32x4;
typedef __attribute__((ext_vector_type(4))) unsigned short us4;
typedef __attribute__((ext_vector_type(8))) unsigned short us8;
typedef __attribute__((ext_vector_type(4))) unsigned int ui4;
typedef __attribute__((ext_vector_type(2))) unsigned int ui2;
typedef _Float16 __attribute__((ext_vector_type(2))) h2;
typedef _Float16 __attribute__((ext_vector_type(8))) h8;

static __device__ __forceinline__ unsigned int pk16(float a, float b){
  return __builtin_bit_cast(unsigned int, __builtin_amdgcn_cvt_pkrtz(a, b));
}
static __device__ __forceinline__ h2 uph(unsigned int u){
  return __builtin_bit_cast(h2, u);
}
static __device__ __forceinline__ float h2f(unsigned short h){
  return (float)__builtin_bit_cast(_Float16, h);
}
static __device__ __forceinline__ unsigned short f16b(float x){
  return __builtin_bit_cast(unsigned short, (_Float16)x);
}
static __device__ __forceinline__ h8 ldh8(const unsigned short* p){
  return __builtin_bit_cast(h8, *(const us8*)p);
}
#define FDOT2(a, b, c) __builtin_amdgcn_fdot2((a), (b), (c), false)
#define MFMA16(a, b, c) __builtin_amdgcn_mfma_f32_16x16x32_f16((a), (b), (c), 0, 0, 0)

// ---------------------------------------------------------------------------
// Prep: W1/W2 ROW-MAJOR f16 (MFMA B-fragments); W3 k-pair packed (fdot2).
//   W1R us [640][256]: rows 0..511 -> M_h rows (n=h*256+m); 512..639 -> Wc
//   W2R us [256][256]: Wv row-major
//   W3P uint [128][128]: Wx^T k-pair packed
// ws total: 327680 + 131072 + 65536 = 512 KiB.
// ---------------------------------------------------------------------------
__global__ void prep_kernel(const float* __restrict__ Wq, const float* __restrict__ Wk,
                            const float* __restrict__ Wv, const float* __restrict__ Wc,
                            const float* __restrict__ Wx, unsigned short* __restrict__ wsp){
  unsigned short* W1R = wsp;                                   // [640][256]
  unsigned short* W2R = wsp + 640*256;                         // [256][256]
  unsigned int*   W3P = (unsigned int*)(wsp + 640*256 + 256*256); // [128][128]
  const int n = blockIdx.x;
  const int k = threadIdx.x;
  float val;
  if (n < 512){
    const int h = n >> 8, m = n & 255;
    const float* wq = Wq + h*128*256 + k;
    const float* wk = Wk + h*128*256 + m;
    float s = 0.f;
    for (int d = 0; d < 128; ++d) s += wq[d*256] * wk[d*256];
    val = s;
  } else if (n < 640){
    val = Wc[(n-512)*256 + k];
  } else if (n < 896){
    val = Wv[(n-640)*256 + k];
  } else {
    val = Wx[(n-896)*256 + k];
  }
  if (n < 640){
    W1R[n*256 + k] = f16b(val);
  } else if (n < 896){
    W2R[(n-640)*256 + k] = f16b(val);
  } else {
    const float vo = __shfl_xor(val, 1, 64);
    if ((k & 1) == 0)
      W3P[(k >> 1)*128 + (n-896)] = pk16(val, vo);
  }
}

// ---------------------------------------------------------------------------
// Fused kernel. Phase A (R19-proven MFMA) + Phase C via MFMA with
// in-register LayerNorm (shfl partials + 16B/row LDS exchange).
// Phase B verbatim R12; Phase E verbatim R12 fdot2.
// Wave roles in A/C: rowg=wid>>1 (16-row group), colh=wid&1 (column half).
// LDS s_ctil us[32][520]: center f16 (cells 256..511) -> ctil 0..511 (A..B)
//   -> wbuf+agg (B..C) -> LN partials cells 256..263 -> ctx_n f16 cells 0..255.
// ---------------------------------------------------------------------------
__global__ __launch_bounds__(256, 4) void fused_kernel(
    const float* __restrict__ center, const float* __restrict__ nbr,
    const float* __restrict__ ew, const float* __restrict__ gamma,
    const float* __restrict__ beta, const unsigned short* __restrict__ Wall,
    float* __restrict__ out)
{
  __shared__ __align__(16) unsigned short s_ctil[BR*520];

  const int tid  = threadIdx.x;
  const int wid  = tid >> 6;
  const int lane = tid & 63;
  const int b0   = blockIdx.x * BR;

  const unsigned short* W1R = Wall;                                 // [640][256]
  const unsigned short* W2R = Wall + 640*256;                       // [256][256]
  const unsigned int*   W3P = (const unsigned int*)(Wall + 640*256 + 256*256); // [128][128]

  const int rt = tid >> 5;     // 0..7  (rows 4rt..4rt+3; E fdot2 map)
  const int ct = tid & 31;     // 0..31 (col quad; E fdot2 map)

  // ---- stage center rows 8w..8w+7 as f16 -> cells 256..511 ----
  {
    const int sr = tid >> 3;            // 0..31, wave-local rows
    const int fc = (tid & 7) * 32;      // f16 col base
    const float* cp = center + ((long)(b0 + sr) << 8) + fc;
    #pragma unroll
    for (int it = 0; it < 4; ++it){
      float4 a = *(const float4*)(cp + it*8);
      float4 b = *(const float4*)(cp + it*8 + 4);
      ui4 v = {pk16(a.x,a.y), pk16(a.z,a.w), pk16(b.x,b.y), pk16(b.z,b.w)};
      *(ui4*)&s_ctil[sr*520 + 256 + fc + it*8] = v;
    }
  }
  __syncthreads();

  // ---- Phase A via MFMA: [32x256]@[256x640] -> ctil (LDS) + out-left ----
  {
    const int rowg = wid >> 1;       // 16-row group
    const int colh = wid & 1;        // 20-tile column half
    const int l15 = lane & 15, lq = lane >> 4;
    h8 af[8];
    #pragma unroll
    for (int kk = 0; kk < 8; ++kk)
      af[kk] = __builtin_bit_cast(h8,
        *(const us8*)&s_ctil[(rowg*16 + l15)*520 + 256 + kk*32 + lq*8]);
    __syncthreads();   // all fragment loads done before ctil overwrites cells 256+
    #pragma unroll 1
    for (int c0t = 0; c0t < 20; c0t += 5){
      f32x4 acc[5];
      #pragma unroll
      for (int u = 0; u < 5; ++u) acc[u] = (f32x4){0,0,0,0};
      #pragma unroll
      for (int kk = 0; kk < 8; ++kk)
        #pragma unroll
        for (int u = 0; u < 5; ++u){
          const int gt = colh*20 + c0t + u;
          acc[u] = MFMA16(af[kk], ldh8(W1R + (gt*16 + l15)*256 + kk*32 + lq*8), acc[u]);
        }
      #pragma unroll
      for (int u = 0; u < 5; ++u){
        const int gt = colh*20 + c0t + u;
        if (gt < 32){
          #pragma unroll
          for (int j = 0; j < 4; ++j)
            s_ctil[(rowg*16 + lq*4 + j)*520 + gt*16 + l15] = f16b(acc[u][j]);
        } else {
          #pragma unroll
          for (int j = 0; j < 4; ++j)
            out[((long)(b0 + rowg*16 + lq*4 + j) << 8) + (gt-32)*16 + l15] = acc[u][j];
        }
      }
    }
  }
  __syncthreads();

  // ---- Phase B: attention (VERBATIM round 12), 8 rows/wave ----
  {
    const int myk = ((lane>>4)&1)*8 + ((lane>>3)&1)*4 + ((lane>>2)&1)*2 + ((lane>>1)&1);
    const int myh = lane >> 5;
    #pragma unroll 1
    for (int rr = 0; rr < 8; ++rr){
      const int r = wid*8 + rr;
      const long b = b0 + r;
      float4 c0, c1;
      {
        us4 h0 = *(const us4*)&s_ctil[r*520 + lane*4];
        us4 h1 = *(const us4*)&s_ctil[r*520 + 256 + lane*4];
        c0.x=h2f(h0[0]); c0.y=h2f(h0[1]); c0.z=h2f(h0[2]); c0.w=h2f(h0[3]);
        c1.x=h2f(h1[0]); c1.y=h2f(h1[1]); c1.z=h2f(h1[2]); c1.w=h2f(h1[3]);
      }
      float4 xv[16];
      const float* npt = nbr + ((b << 4) << 8) + lane*4;
      #pragma unroll
      for (int k = 0; k < 16; ++k) xv[k] = *(const float4*)(npt + (k << 8));
      float P0[16], P1[16];
      #pragma unroll
      for (int k = 0; k < 16; ++k){
        P0[k] = xv[k].x*c0.x + xv[k].y*c0.y + xv[k].z*c0.z + xv[k].w*c0.w;
        P1[k] = xv[k].x*c1.x + xv[k].y*c1.y + xv[k].z*c1.z + xv[k].w*c1.w;
      }
      // reduce-scatter: masks 32,16,8,4,2, then final 1
      const int b5 = lane & 32, b4 = lane & 16, b3 = lane & 8, b2 = lane & 4, b1 = lane & 2;
      float Q[16];
      #pragma unroll
      for (int j = 0; j < 16; ++j){
        const float give = b5 ? P0[j] : P1[j];
        const float keep = b5 ? P1[j] : P0[j];
        Q[j] = keep + __shfl_xor(give, 32, 64);
      }
      float R[8];
      #pragma unroll
      for (int j = 0; j < 8; ++j){
        const float give = b4 ? Q[j] : Q[8+j];
        const float keep = b4 ? Q[8+j] : Q[j];
        R[j] = keep + __shfl_xor(give, 16, 64);
      }
      float S[4];
      #pragma unroll
      for (int j = 0; j < 4; ++j){
        const float give = b3 ? R[j] : R[4+j];
        const float keep = b3 ? R[4+j] : R[j];
        S[j] = keep + __shfl_xor(give, 8, 64);
      }
      float T[2];
      #pragma unroll
      for (int j = 0; j < 2; ++j){
        const float give = b2 ? S[j] : S[2+j];
        const float keep = b2 ? S[2+j] : S[j];
        T[j] = keep + __shfl_xor(give, 4, 64);
      }
      float U;
      {
        const float give = b1 ? T[0] : T[1];
        const float keep = b1 ? T[1] : T[0];
        U = keep + __shfl_xor(give, 2, 64);
      }
      const float sfull = U + __shfl_xor(U, 1, 64);   // s[myh][myk]
      const float erk = ew[b*16 + myk];
      const float e = __expf(sfull*SCALE + erk);      // scores O(1): no max-sub
      float dn = e;
      dn += __shfl_xor(dn, 2, 64);
      dn += __shfl_xor(dn, 4, 64);
      dn += __shfl_xor(dn, 8, 64);
      dn += __shfl_xor(dn, 16, 64);
      const float w = e / dn;
      // broadcast via wave-local overlay of head1-ctil cells (c1 already read)
      float* wbuf = (float*)&s_ctil[r*520 + 256];
      wbuf[myh*16 + myk] = w;                         // 2 lanes same addr, same value
      f32x4 wv[8];
      #pragma unroll
      for (int t = 0; t < 8; ++t) wv[t] = ((const f32x4*)wbuf)[t];
      float4 agg0 = {0,0,0,0}, agg1 = {0,0,0,0};
      #pragma unroll
      for (int k = 0; k < 16; ++k){
        const float w0 = wv[k>>2][k&3];
        const float w1 = wv[4 + (k>>2)][k&3];
        agg0.x += w0*xv[k].x; agg0.y += w0*xv[k].y; agg0.z += w0*xv[k].z; agg0.w += w0*xv[k].w;
        agg1.x += w1*xv[k].x; agg1.y += w1*xv[k].y; agg1.z += w1*xv[k].z; agg1.w += w1*xv[k].w;
      }
      ui2 v0 = {pk16(agg0.x, agg0.y), pk16(agg0.z, agg0.w)};
      ui2 v1 = {pk16(agg1.x, agg1.y), pk16(agg1.z, agg1.w)};
      *(ui2*)&s_ctil[r*520 + lane*4]       = v0;   // agg0 (WAR on own cells)
      *(ui2*)&s_ctil[r*520 + 256 + lane*4] = v1;   // agg1 (overwrites wbuf after read)
    }
  }
  __syncthreads();   // agg complete; phase C reads cross-wave rows

  // ---- Phase C via MFMA + in-register LayerNorm -> ctx_n f16 (cells 0..255) ----
  {
    const int rowg = wid >> 1;       // 16-row group
    const int colh = wid & 1;        // column half (== head)
    const int l15 = lane & 15, lq = lane >> 4;
    h8 cf[8];
    #pragma unroll
    for (int kk = 0; kk < 8; ++kk)
      cf[kk] = __builtin_bit_cast(h8,
        *(const us8*)&s_ctil[(rowg*16 + l15)*520 + colh*256 + kk*32 + lq*8]);
    f32x4 cacc[8];
    #pragma unroll
    for (int t = 0; t < 8; ++t) cacc[t] = (f32x4){0,0,0,0};
    #pragma unroll
    for (int kk = 0; kk < 8; ++kk)
      #pragma unroll
      for (int t = 0; t < 8; ++t){
        const int col = colh*128 + t*16 + l15;      // ctx col (head = colh)
        cacc[t] = MFMA16(cf[kk], ldh8(W2R + col*256 + kk*32 + lq*8), cacc[t]);
      }
    // partial row sums over this wave's 128-col half (reduce across l15)
    float ps[4], pq[4];
    #pragma unroll
    for (int j = 0; j < 4; ++j){
      float sm = 0.f, qm = 0.f;
      #pragma unroll
      for (int t = 0; t < 8; ++t){ const float x = cacc[t][j]; sm += x; qm += x*x; }
      #pragma unroll
      for (int m = 1; m <= 8; m <<= 1){
        sm += __shfl_xor(sm, m, 64);
        qm += __shfl_xor(qm, m, 64);
      }
      ps[j] = sm; pq[j] = qm;
    }
    __syncthreads();   // all cf reads done before partial writes hit cells 256..263
    if (l15 == 0){
      #pragma unroll
      for (int j = 0; j < 4; ++j){
        float* pp = (float*)&s_ctil[(rowg*16 + lq*4 + j)*520 + 256];
        pp[colh*2]     = ps[j];
        pp[colh*2 + 1] = pq[j];
      }
    }
    __syncthreads();   // partials visible to the wave pair
    float gv[8], bv[8];
    #pragma unroll
    for (int t = 0; t < 8; ++t){
      const int col = colh*128 + t*16 + l15;
      gv[t] = gamma[col];
      bv[t] = beta[col];
    }
    #pragma unroll
    for (int j = 0; j < 4; ++j){
      const int r = rowg*16 + lq*4 + j;
      const float* pp = (const float*)&s_ctil[r*520 + 256];
      const float sm = pp[0] + pp[2];
      const float qm = pp[1] + pp[3];
      const float mu  = sm * (1.f/256.f);
      const float var = qm * (1.f/256.f) - mu*mu;
      const float rs  = rsqrtf(var + 1e-5f);
      #pragma unroll
      for (int t = 0; t < 8; ++t){
        const int col = colh*128 + t*16 + l15;
        s_ctil[r*520 + col] = f16b((cacc[t][j] - mu)*rs*gv[t] + bv[t]);
      }
    }
  }
  __syncthreads();   // ctx_n complete (both halves) before E

  // ---- Phase E: out-right = ctx_n @ Wx^T (VERBATIM R12 fdot2) ----
  {
    f32x4 eacc[4];
    #pragma unroll
    for (int rr = 0; rr < 4; ++rr) eacc[rr] = (f32x4){0,0,0,0};
    #pragma unroll 1
    for (int k0 = 0; k0 < 256; k0 += 8){
      ui4 a8[4];
      #pragma unroll
      for (int rr = 0; rr < 4; ++rr)
        a8[rr] = *(const ui4*)&s_ctil[(4*rt+rr)*520 + k0];
      #pragma unroll
      for (int kp = 0; kp < 4; ++kp){
        const ui4 w = ((const ui4*)(W3P + ((k0>>1) + kp)*128))[ct];
        #pragma unroll
        for (int rr = 0; rr < 4; ++rr){
          const h2 x = uph(a8[rr][kp]);
          #pragma unroll
          for (int j = 0; j < 4; ++j)
            eacc[rr][j] = FDOT2(x, uph(w[j]), eacc[rr][j]);
        }
      }
    }
    #pragma unroll
    for (int rr = 0; rr < 4; ++rr)
      *(f32x4*)&out[((long)(b0 + 4*rt + rr) << 8) + 128 + ct*4] = eacc[rr];
  }
}

extern "C" void kernel_launch(void* const* d_in, const int* in_sizes, int n_in,
                              void* d_out, int out_size, void* d_ws, size_t ws_size,
                              hipStream_t stream){
  const float* center = (const float*)d_in[0];
  const float* nbr    = (const float*)d_in[1];
  const float* ew     = (const float*)d_in[2];
  const float* Wq     = (const float*)d_in[3];
  const float* Wk     = (const float*)d_in[4];
  const float* Wv     = (const float*)d_in[5];
  const float* Wc     = (const float*)d_in[6];
  const float* Wx     = (const float*)d_in[7];
  const float* gamma  = (const float*)d_in[8];
  const float* beta   = (const float*)d_in[9];
  (void)in_sizes; (void)n_in; (void)out_size;

  unsigned short* W = (unsigned short*)d_ws;   // 512 KiB of workspace
  (void)ws_size;

  prep_kernel<<<1024, 256, 0, stream>>>(Wq, Wk, Wv, Wc, Wx, W);
  fused_kernel<<<Bsz/BR, 256, 0, stream>>>(center, nbr, ew, gamma, beta, W, (float*)d_out);
}